// Round 10
// baseline (1021.522 us; speedup 1.0000x reference)
//
#include <hip/hip_runtime.h>
#include <hip/hip_bf16.h>
#include <math.h>

// NeuralCDE fused kernel, round 10.
// 512 blocks x 256 threads (4 waves); block owns 8 batch rows for all 256
// RK4 steps -> 2 independent blocks co-resident per CU (launch_bounds(256,2),
// VGPR<=128). Independent barrier domains de-phase and hide each other's
// LDS/MFMA/barrier latency — the thing 4 lockstep waves could never do.
// Structure is exactly round 5 (805us best): wave owns 32 output channels
// (2 M-tiles), operand-swapped MFMA (W^T=A regs, X^T=B from LDS), bias in
// accumulator init, cvt_pk+ds_write_b64 stores, coeffs register-prefetched.
// MFMA n-cols 8..15 carry row-duplicates (l15&7); D-stores masked to l15<8.

typedef short bf16x8 __attribute__((ext_vector_type(8)));
typedef float f32x4  __attribute__((ext_vector_type(4)));
typedef unsigned int u32x2 __attribute__((ext_vector_type(2)));

__device__ __forceinline__ f32x4 MFMA16(bf16x8 a, bf16x8 b, f32x4 c) {
  return __builtin_amdgcn_mfma_f32_16x16x32_bf16(a, b, c, 0, 0, 0);
}

__device__ __forceinline__ unsigned short f2bf(float x) {  // weight prep only
  unsigned int u = __float_as_uint(x);
  u += 0x7FFFu + ((u >> 16) & 1u);
  return (unsigned short)(u >> 16);
}

__device__ __forceinline__ unsigned int cvt_pk(float lo, float hi) {
  unsigned int r;  // D[15:0]=bf16(lo), D[31:16]=bf16(hi), RNE
  asm("v_cvt_pk_bf16_f32 %0, %1, %2" : "=v"(r) : "v"(lo), "v"(hi));
  return r;
}

// raw barrier: LDS-drain only (keeps global prefetch loads in flight).
__device__ __forceinline__ void barrier_lgkm() {
  asm volatile("s_waitcnt lgkmcnt(0)" ::: "memory");
  __builtin_amdgcn_s_barrier();
  asm volatile("" ::: "memory");
}

__global__ __launch_bounds__(256, 2) void cde_fused(
    const float* __restrict__ z0, const float* __restrict__ coeffs,
    const float* __restrict__ W1, const float* __restrict__ b1,
    const float* __restrict__ W2, const float* __restrict__ b2,
    const float* __restrict__ W3, const float* __restrict__ b3,
    const float* __restrict__ Wr, const float* __restrict__ br,
    float* __restrict__ out) {
  // [2][8 rows][136 ch] shorts; row stride 272 B; buffer stride 2176 B.
  __shared__ __align__(16) unsigned short zbuf[2][8][136];
  char* const lds = (char*)zbuf;

  const int tid  = (int)threadIdx.x;
  const int lane = tid & 63;
  const int wv   = tid >> 6;        // wave 0..3
  const int l15  = lane & 15;       // MFMA n-col / weight-tile row (0..15)
  const int q    = lane >> 4;       // 0..3
  const int rowl = l15 & 7;         // batch row within tile (cols 8-15 dup)
  const bool wlane = (l15 < 8);     // lanes whose n-col is a real row
  const int cb0  = wv * 32;         // wave's channel base (2 M-tiles of 16)
  const int row0 = (int)blockIdx.x * 8;

  // B-frag read (X^T): row rowl, ch 32ks+8q.. -> byte rowl*272 + 64ks + 16q
  const int rdbyte = rowl * 272 + q * 16;
  // D store: row rowl, ch cb0+16mt+4q.. (masked to wlane)
  const int wrbyte0 = rowl * 272 + (cb0 + 4 * q) * 2;
  const int wrbyte1 = wrbyte0 + 32;

  // ------------- weight A-frags (one-time, 96 VGPRs) -------------
  // A[m][k]: lane(q,l15) of tile mt holds W[32ks+8q+i][cb0+16mt+l15]
  bf16x8 wf1[2][4], wf2[2][4], wf3[2][4];
#pragma unroll
  for (int mt = 0; mt < 2; ++mt) {
    const int col = cb0 + 16 * mt + l15;
#pragma unroll
    for (int ks = 0; ks < 4; ++ks) {
      bf16x8 fa, fb, fc;
#pragma unroll
      for (int i = 0; i < 8; ++i) {
        const int k = ks * 32 + q * 8 + i;
        fa[i] = (short)f2bf(W1[k * 128 + col]);
        fb[i] = (short)f2bf(W2[k * 128 + col]);
        fc[i] = (short)f2bf(W3[k * 128 + col]);
      }
      wf1[mt][ks] = fa; wf2[mt][ks] = fb; wf3[mt][ks] = fc;
    }
  }
  // biases (accumulator init): D element r of tile mt = ch cb0+16mt+4q+r
  f32x4 bv1[2], bv2[2], bv3[2];
#pragma unroll
  for (int mt = 0; mt < 2; ++mt) {
    bv1[mt] = *(const f32x4*)(b1 + cb0 + 16 * mt + 4 * q);
    bv2[mt] = *(const f32x4*)(b2 + cb0 + 16 * mt + 4 * q);
    bv3[mt] = *(const f32x4*)(b3 + cb0 + 16 * mt + 4 * q);
  }

  // ------------- coeff registers (e = mt*4+r -> row rowl, ch cb0+16mt+4q+r) --
  f32x4 cf[8];
  auto coeff_load = [&](int p) {
    const float* cb = coeffs + ((size_t)(row0 + rowl) * 64 + p) * 512;
#pragma unroll
    for (int mt = 0; mt < 2; ++mt)
#pragma unroll
      for (int r = 0; r < 4; ++r)
        cf[mt * 4 + r] = *(const f32x4*)(cb + (cb0 + 16 * mt + 4 * q + r) * 4);
  };
  float c1v[8], c2b[8], c3b[8];  // c1, 2*c2, 3*c3
  auto coeff_adopt = [&]() {
#pragma unroll
    for (int e = 0; e < 8; ++e) {
      c1v[e] = cf[e][1]; c2b[e] = 2.f * cf[e][2]; c3b[e] = 3.f * cf[e][3];
    }
  };

  auto stv = [&](int wb, const float (&h)[8]) {  // 8 ch -> two b64 writes
    if (wlane) {
      u32x2 w0, w1;
      w0[0] = cvt_pk(h[0], h[1]); w0[1] = cvt_pk(h[2], h[3]);
      w1[0] = cvt_pk(h[4], h[5]); w1[1] = cvt_pk(h[6], h[7]);
      *(u32x2*)(lds + (wb * 2176 + wrbyte0)) = w0;
      *(u32x2*)(lds + (wb * 2176 + wrbyte1)) = w1;
    }
  };

  // ------------- prologue -------------
  float zr[8];
  {
    const float* zp = z0 + (size_t)(row0 + rowl) * 128;
    const f32x4 za = *(const f32x4*)(zp + cb0 + 4 * q);
    const f32x4 zb = *(const f32x4*)(zp + cb0 + 16 + 4 * q);
#pragma unroll
    for (int r = 0; r < 4; ++r) { zr[r] = za[r]; zr[4 + r] = zb[r]; }
  }
  coeff_load(0);
  coeff_adopt();
  {
    float h[8];
#pragma unroll
    for (int e = 0; e < 8; ++e) h[e] = zr[e];
    stv(0, h);
  }
  barrier_lgkm();

  float kx[8], sacc[8], dxb[8];

  // one layer: out[mt] = W^T * X^T + bias ; 4 shared B-frags, 8 MFMA
  auto layer = [&](const bf16x8(&wf)[2][4], const f32x4(&bias)[2], int rb,
                   f32x4& A0, f32x4& A1) {
    const char* base = lds + rb * 2176 + rdbyte;
    bf16x8 x0 = *(const bf16x8*)(base);
    bf16x8 x1 = *(const bf16x8*)(base + 64);
    bf16x8 x2 = *(const bf16x8*)(base + 128);
    bf16x8 x3 = *(const bf16x8*)(base + 192);
    A0 = bias[0]; A1 = bias[1];
    A0 = MFMA16(wf[0][0], x0, A0); A1 = MFMA16(wf[1][0], x0, A1);
    A0 = MFMA16(wf[0][1], x1, A0); A1 = MFMA16(wf[1][1], x1, A1);
    A0 = MFMA16(wf[0][2], x2, A0); A1 = MFMA16(wf[1][2], x2, A1);
    A0 = MFMA16(wf[0][3], x3, A0); A1 = MFMA16(wf[1][3], x3, A1);
  };

  // one MLP eval; input in buffer sp; result (incl. b3) -> kx
  auto run_f = [&](int sp) {
    f32x4 A0, A1;
    float h[8];
    layer(wf1, bv1, sp, A0, A1);
#pragma unroll
    for (int r = 0; r < 4; ++r) {  // ELU(v) = max(v, exp(min(v,0))-1)
      h[r]     = fmaxf(A0[r], __expf(fminf(A0[r], 0.f)) - 1.f);
      h[4 + r] = fmaxf(A1[r], __expf(fminf(A1[r], 0.f)) - 1.f);
    }
    stv(sp ^ 1, h);
    barrier_lgkm();
    layer(wf2, bv2, sp ^ 1, A0, A1);
#pragma unroll
    for (int r = 0; r < 4; ++r) {
      h[r] = fmaxf(A0[r], 0.f); h[4 + r] = fmaxf(A1[r], 0.f);  // ReLU
    }
    stv(sp, h);
    barrier_lgkm();
    layer(wf3, bv3, sp, A0, A1);
#pragma unroll
    for (int r = 0; r < 4; ++r) { kx[r] = A0[r]; kx[4 + r] = A1[r]; }
  };

  // ------------- main loop: 64 pieces x 4 unrolled sub-steps -------------
#pragma unroll 1
  for (int p = 0; p < 64; ++p) {
    const bool pre = p < 63;
    if (pre) coeff_load(p + 1);  // prefetch next piece into regs

#pragma unroll
    for (int sub = 0; sub < 4; ++sub) {
      const float s0 = 0.25f * (float)sub;  // compile-time

      // ---- stage 1: k1 = f(z)*dX(s0); input buf0 ----
      run_f(0);
      {
        float h[8];
#pragma unroll
        for (int e = 0; e < 8; ++e) {
          const float dx = c1v[e] + (c2b[e] + c3b[e] * s0) * s0;
          kx[e] *= dx; sacc[e] = kx[e];
          h[e] = zr[e] + 0.125f * kx[e];
        }
        stv(1, h);
      }
      barrier_lgkm();

      // ---- stage 2: k2 at s0+0.125; input buf1 ----
      run_f(1);
      {
        const float sb = s0 + 0.125f;
        float h[8];
#pragma unroll
        for (int e = 0; e < 8; ++e) {
          dxb[e] = c1v[e] + (c2b[e] + c3b[e] * sb) * sb;
          kx[e] *= dxb[e]; sacc[e] += 2.f * kx[e];
          h[e] = zr[e] + 0.125f * kx[e];
        }
        stv(0, h);
      }
      barrier_lgkm();

      // ---- stage 3: k3 at same s as k2 (dx reused); input buf0 ----
      run_f(0);
      {
        float h[8];
#pragma unroll
        for (int e = 0; e < 8; ++e) {
          kx[e] *= dxb[e]; sacc[e] += 2.f * kx[e];
          h[e] = zr[e] + 0.25f * kx[e];
        }
        stv(1, h);
      }
      barrier_lgkm();

      // ---- stage 4: k4 at t+dt; input buf1 ----
      run_f(1);
      if (sub == 3) {
        if (pre) {
#pragma unroll
          for (int e = 0; e < 8; ++e) kx[e] *= cf[e][1];  // next piece, s=0
        } else {
#pragma unroll
          for (int e = 0; e < 8; ++e) kx[e] *= (c1v[e] + c2b[e] + c3b[e]);  // s=1
        }
      } else {
        const float sc = s0 + 0.25f;
#pragma unroll
        for (int e = 0; e < 8; ++e)
          kx[e] *= c1v[e] + (c2b[e] + c3b[e] * sc) * sc;
      }
      {
        float h[8];
#pragma unroll
        for (int e = 0; e < 8; ++e) {
          sacc[e] += kx[e];
          zr[e] += (0.25f / 6.f) * sacc[e];
          h[e] = zr[e];
        }
        stv(0, h);  // next step's f-input -> buf0
      }
      barrier_lgkm();
    }
    if (pre) coeff_adopt();
  }

  // ------------- readout: out = zT @ Wr + br -------------
  // reuse LDS as fp32 zf[8][132] (4224 B <= 8704 B)
  __syncthreads();
  if (wlane) {
    float* zf = (float*)lds;
    *(f32x4*)(zf + rowl * 132 + cb0 + 4 * q)      = f32x4{zr[0], zr[1], zr[2], zr[3]};
    *(f32x4*)(zf + rowl * 132 + cb0 + 16 + 4 * q) = f32x4{zr[4], zr[5], zr[6], zr[7]};
  }
  __syncthreads();
  if (tid < 80) {
    const int row = tid / 10, o = tid - row * 10;
    const float* zf = (const float*)lds;
    float acc = br[o];
#pragma unroll 4
    for (int ch = 0; ch < 128; ++ch)
      acc = fmaf(zf[row * 132 + ch], Wr[ch * 10 + o], acc);
    out[(size_t)(row0 + row) * 10 + o] = acc;
  }
}

extern "C" void kernel_launch(void* const* d_in, const int* in_sizes, int n_in,
                              void* d_out, int out_size, void* d_ws, size_t ws_size,
                              hipStream_t stream) {
  const float* z0     = (const float*)d_in[0];
  const float* coeffs = (const float*)d_in[1];
  const float* W1 = (const float*)d_in[2]; const float* b1 = (const float*)d_in[3];
  const float* W2 = (const float*)d_in[4]; const float* b2 = (const float*)d_in[5];
  const float* W3 = (const float*)d_in[6]; const float* b3 = (const float*)d_in[7];
  const float* Wr = (const float*)d_in[8]; const float* br = (const float*)d_in[9];
  hipLaunchKernelGGL(cde_fused, dim3(512), dim3(256), 0, stream,
                     z0, coeffs, W1, b1, W2, b2, W3, b3, Wr, br, (float*)d_out);
}

// Round 12
// 693.343 us; speedup vs baseline: 1.4733x; 1.4733x over previous
//
#include <hip/hip_runtime.h>
#include <hip/hip_bf16.h>
#include <math.h>

// NeuralCDE fused kernel, round 12 = round 11 race-hardened.
// 256 blocks x 256 threads (4 waves); block owns 16 batch rows for all 256
// RK4 steps; wave w owns output channels [32w,32w+32). Operand-swapped MFMA
// (W^T = A in regs, X^T = B from LDS) with the diagonal register identity
// (k = 32*slice + 16(i>>2) + 4q + (i&3)): a wave's D-frag after act+cvt_pk IS
// its own-slice B-operand -> 2 own-slice MFMAs + bias-init issue PRE-barrier,
// 3 ds_read_b128 post-barrier, exchange write is one ds_write_b128. Weight
// frags stored rotation-ordered (wave w keeps slice (w+j)&3 at index j) so
// all hot-loop indices are compile-time literals.
// vs round 11 (715us, post-timing DIVERGED): all inter-wave synchronization
// uses real __syncthreads() (proper fence+barrier semantics) instead of the
// hand-rolled lgkmcnt+s_barrier asm — eliminating the suspected asm-fence
// race at the cost of vmcnt(0) drains (~one per piece hits the coeff
// prefetch).

typedef short bf16x8 __attribute__((ext_vector_type(8)));
typedef float f32x4  __attribute__((ext_vector_type(4)));
typedef unsigned int u32x4 __attribute__((ext_vector_type(4)));

__device__ __forceinline__ f32x4 MFMA16(bf16x8 a, bf16x8 b, f32x4 c) {
  return __builtin_amdgcn_mfma_f32_16x16x32_bf16(a, b, c, 0, 0, 0);
}

__device__ __forceinline__ unsigned short f2bf(float x) {  // weight prep only
  unsigned int u = __float_as_uint(x);
  u += 0x7FFFu + ((u >> 16) & 1u);
  return (unsigned short)(u >> 16);
}

__device__ __forceinline__ unsigned int cvt_pk(float lo, float hi) {
  unsigned int r;  // D[15:0]=bf16(lo), D[31:16]=bf16(hi), RNE
  asm("v_cvt_pk_bf16_f32 %0, %1, %2" : "=v"(r) : "v"(lo), "v"(hi));
  return r;
}

__global__ __launch_bounds__(256, 1) void cde_fused(
    const float* __restrict__ z0, const float* __restrict__ coeffs,
    const float* __restrict__ W1, const float* __restrict__ b1,
    const float* __restrict__ W2, const float* __restrict__ b2,
    const float* __restrict__ W3, const float* __restrict__ b3,
    const float* __restrict__ Wr, const float* __restrict__ br,
    float* __restrict__ out) {
  // [2][16 rows][136 shorts]; row stride 272 B; slice s at byte-offset 64s.
  __shared__ __align__(16) unsigned short zbuf[2][16][136];
  char* const lds = (char*)zbuf;

  const int tid  = (int)threadIdx.x;
  const int lane = tid & 63;
  const int wv   = tid >> 6;        // wave 0..3 (owns k-slice wv)
  const int l15  = lane & 15;       // batch row within tile
  const int q    = lane >> 4;       // 0..3
  const int row0 = (int)blockIdx.x * 16;

  // exchange addresses: slice s lives at byte l15*272 + 64s + 16q
  const int exb  = l15 * 272 + 16 * q;
  const int ownb = exb + 64 * wv;                       // our b128 write
  const int off1 = exb + 64 * ((wv + 1) & 3);           // read, rotation j=1
  const int off2 = exb + 64 * ((wv + 2) & 3);           // j=2
  const int off3 = exb + 64 * ((wv + 3) & 3);           // j=3

  // ------------- weight A-frags, rotation-ordered, B-identity K-dim ---------
  // index [mt][j] holds slice s=(wv+j)&3: elem i = W[32s+16(i>>2)+4q+(i&3)][col]
  bf16x8 wf1[2][4], wf2[2][4], wf3[2][4];
#pragma unroll
  for (int mt = 0; mt < 2; ++mt) {
    const int col = 32 * wv + 16 * mt + l15;
#pragma unroll
    for (int js = 0; js < 4; ++js) {
      const int s = (wv + js) & 3;
      bf16x8 fa, fb, fc;
#pragma unroll
      for (int i = 0; i < 8; ++i) {
        const int k = 32 * s + 16 * (i >> 2) + 4 * q + (i & 3);
        fa[i] = (short)f2bf(W1[k * 128 + col]);
        fb[i] = (short)f2bf(W2[k * 128 + col]);
        fc[i] = (short)f2bf(W3[k * 128 + col]);
      }
      wf1[mt][js] = fa; wf2[mt][js] = fb; wf3[mt][js] = fc;
    }
  }
  // biases (accumulator init): D elem r of tile mt = ch 32wv+16mt+4q+r
  f32x4 bv1[2], bv2[2], bv3[2];
#pragma unroll
  for (int mt = 0; mt < 2; ++mt) {
    bv1[mt] = *(const f32x4*)(b1 + 32 * wv + 16 * mt + 4 * q);
    bv2[mt] = *(const f32x4*)(b2 + 32 * wv + 16 * mt + 4 * q);
    bv3[mt] = *(const f32x4*)(b3 + 32 * wv + 16 * mt + 4 * q);
  }

  // ------------- coeff registers (e = mt*4+r -> row l15, ch 32wv+16mt+4q+r) --
  f32x4 cf[8];
  auto coeff_load = [&](int p) {
    const float* cb = coeffs + ((size_t)(row0 + l15) * 64 + p) * 512;
#pragma unroll
    for (int mt = 0; mt < 2; ++mt)
#pragma unroll
      for (int r = 0; r < 4; ++r)
        cf[mt * 4 + r] = *(const f32x4*)(cb + (32 * wv + 16 * mt + 4 * q + r) * 4);
  };
  float c1v[8], c2b[8], c3b[8];  // c1, 2*c2, 3*c3
  auto coeff_adopt = [&]() {
#pragma unroll
    for (int e = 0; e < 8; ++e) {
      c1v[e] = cf[e][1]; c2b[e] = 2.f * cf[e][2]; c3b[e] = 3.f * cf[e][3];
    }
  };

  // own B-frag registers (packed words, doubles as the LDS exchange payload)
  u32x4 zb;
  auto emit = [&](const float(&h)[8], int wbuf) {  // pack + keep + write b128
    u32x4 t;
    t[0] = cvt_pk(h[0], h[1]); t[1] = cvt_pk(h[2], h[3]);
    t[2] = cvt_pk(h[4], h[5]); t[3] = cvt_pk(h[6], h[7]);
    zb = t;
    *(u32x4*)(lds + wbuf * 4352 + ownb) = t;
  };

  // ------------- prologue -------------
  float zr[8];
  {
    const float* zp = z0 + (size_t)(row0 + l15) * 128 + 32 * wv + 4 * q;
    const f32x4 za = *(const f32x4*)zp;
    const f32x4 zc = *(const f32x4*)(zp + 16);
#pragma unroll
    for (int r = 0; r < 4; ++r) { zr[r] = za[r]; zr[4 + r] = zc[r]; }
  }
  coeff_load(0);
  coeff_adopt();
  {
    float h[8];
#pragma unroll
    for (int e = 0; e < 8; ++e) h[e] = zr[e];
    emit(h, 0);
  }

  float kx[8], sacc[8], dxb[8], dxm[8];
#pragma unroll
  for (int e = 0; e < 8; ++e) dxm[e] = c1v[e];  // dX at t=0 (s=0, piece 0)

  // one layer: 2 own-slice MFMAs pre-barrier (from zb regs), then 3 reads +
  // 6 MFMAs; single depth-4 chain per tile; ALL array indices literal.
  auto layer = [&](const bf16x8(&wf)[2][4], const f32x4(&bv)[2], int rb,
                   f32x4& A0, f32x4& A1) {
    const bf16x8 xo = __builtin_bit_cast(bf16x8, zb);
    f32x4 a0 = MFMA16(wf[0][0], xo, bv[0]);
    f32x4 a1 = MFMA16(wf[1][0], xo, bv[1]);
    __syncthreads();
    const char* base = lds + rb * 4352;
    const bf16x8 x1 = *(const bf16x8*)(base + off1);
    const bf16x8 x2 = *(const bf16x8*)(base + off2);
    const bf16x8 x3 = *(const bf16x8*)(base + off3);
    a0 = MFMA16(wf[0][1], x1, a0);
    a1 = MFMA16(wf[1][1], x1, a1);
    a0 = MFMA16(wf[0][2], x2, a0);
    a1 = MFMA16(wf[1][2], x2, a1);
    a0 = MFMA16(wf[0][3], x3, a0);
    a1 = MFMA16(wf[1][3], x3, a1);
    A0 = a0; A1 = a1;
  };

  // one MLP eval; exchange buffers: L1 rd sp wr sp^1, L2 rd sp^1 wr sp,
  // L3 rd sp; result (incl. b3) -> kx
  auto run_f = [&](int sp) {
    f32x4 A0, A1;
    float h[8];
    layer(wf1, bv1, sp, A0, A1);
#pragma unroll
    for (int r = 0; r < 4; ++r) {  // ELU(v) = max(v, exp(min(v,0))-1)
      h[r]     = fmaxf(A0[r], __expf(fminf(A0[r], 0.f)) - 1.f);
      h[4 + r] = fmaxf(A1[r], __expf(fminf(A1[r], 0.f)) - 1.f);
    }
    emit(h, sp ^ 1);
    layer(wf2, bv2, sp ^ 1, A0, A1);
#pragma unroll
    for (int r = 0; r < 4; ++r) {
      h[r] = fmaxf(A0[r], 0.f); h[4 + r] = fmaxf(A1[r], 0.f);  // ReLU
    }
    emit(h, sp);
    layer(wf3, bv3, sp, A0, A1);
#pragma unroll
    for (int r = 0; r < 4; ++r) { kx[r] = A0[r]; kx[4 + r] = A1[r]; }
  };

  // ------------- main loop: 64 pieces x 4 unrolled substeps -------------
#pragma unroll 1
  for (int p = 0; p < 64; ++p) {
    const bool pre = p < 63;
    if (pre) coeff_load(p + 1);  // prefetch next piece into regs (vmem queue)

#pragma unroll
    for (int sub = 0; sub < 4; ++sub) {
      const float s0 = 0.25f * (float)sub;  // compile-time

      // ---- stage 1: k1 = f(z)*dX(s0); dx carried in dxm ----
      run_f(0);
      {
        float h[8];
#pragma unroll
        for (int e = 0; e < 8; ++e) {
          kx[e] *= dxm[e]; sacc[e] = kx[e];
          h[e] = fmaf(0.125f, kx[e], zr[e]);
        }
        emit(h, 1);
      }

      // ---- stage 2: k2 at s0+0.125 ----
      run_f(1);
      {
        const float sb = s0 + 0.125f;
        float h[8];
#pragma unroll
        for (int e = 0; e < 8; ++e) {
          dxb[e] = c1v[e] + (c2b[e] + c3b[e] * sb) * sb;
          kx[e] *= dxb[e]; sacc[e] += 2.f * kx[e];
          h[e] = fmaf(0.125f, kx[e], zr[e]);
        }
        emit(h, 0);
      }

      // ---- stage 3: k3 at same s as k2 (dx reused) ----
      run_f(0);
      {
        float h[8];
#pragma unroll
        for (int e = 0; e < 8; ++e) {
          kx[e] *= dxb[e]; sacc[e] += 2.f * kx[e];
          h[e] = fmaf(0.25f, kx[e], zr[e]);
        }
        emit(h, 1);
      }

      // ---- stage 4: k4 at t+dt; dxm set for NEXT stage 1 too ----
      run_f(1);
      if (sub == 3) {
        if (pre) {
#pragma unroll
          for (int e = 0; e < 8; ++e) dxm[e] = cf[e][1];  // next piece, s=0
        } else {
#pragma unroll
          for (int e = 0; e < 8; ++e) dxm[e] = c1v[e] + c2b[e] + c3b[e];  // s=1
        }
      } else {
        const float sc = s0 + 0.25f;
#pragma unroll
        for (int e = 0; e < 8; ++e)
          dxm[e] = c1v[e] + (c2b[e] + c3b[e] * sc) * sc;
      }
      {
        float h[8];
#pragma unroll
        for (int e = 0; e < 8; ++e) {
          const float k4 = kx[e] * dxm[e];
          sacc[e] += k4;
          zr[e] = fmaf(0.25f / 6.f, sacc[e], zr[e]);
          h[e] = zr[e];
        }
        emit(h, 0);  // next step's f-input -> buf0
      }
    }
    if (pre) coeff_adopt();
  }

  // ------------- readout: out = zT @ Wr + br -------------
  __syncthreads();  // all exchange reads done; reuse LDS as fp32 zf[16][132]
  {
    float* zf = (float*)lds;
    *(f32x4*)(zf + l15 * 132 + 32 * wv + 4 * q)      = f32x4{zr[0], zr[1], zr[2], zr[3]};
    *(f32x4*)(zf + l15 * 132 + 32 * wv + 16 + 4 * q) = f32x4{zr[4], zr[5], zr[6], zr[7]};
  }
  __syncthreads();
  if (tid < 160) {
    const int row = tid / 10, o = tid - row * 10;
    const float* zf = (const float*)lds;
    float acc = br[o];
#pragma unroll 4
    for (int ch = 0; ch < 128; ++ch)
      acc = fmaf(zf[row * 132 + ch], Wr[ch * 10 + o], acc);
    out[(size_t)(row0 + row) * 10 + o] = acc;
  }
}

extern "C" void kernel_launch(void* const* d_in, const int* in_sizes, int n_in,
                              void* d_out, int out_size, void* d_ws, size_t ws_size,
                              hipStream_t stream) {
  const float* z0     = (const float*)d_in[0];
  const float* coeffs = (const float*)d_in[1];
  const float* W1 = (const float*)d_in[2]; const float* b1 = (const float*)d_in[3];
  const float* W2 = (const float*)d_in[4]; const float* b2 = (const float*)d_in[5];
  const float* W3 = (const float*)d_in[6]; const float* b3 = (const float*)d_in[7];
  const float* Wr = (const float*)d_in[8]; const float* br = (const float*)d_in[9];
  hipLaunchKernelGGL(cde_fused, dim3(256), dim3(256), 0, stream,
                     z0, coeffs, W1, b1, W2, b2, W3, b3, Wr, br, (float*)d_out);
}